// Round 1
// baseline (682.282 us; speedup 1.0000x reference)
//
#include <hip/hip_runtime.h>
#include <hip/hip_fp16.h>
#include <cstdint>
#include <cstddef>

// Problem dims (fixed by the reference)
#define TT 1024
#define BB 64
#define DD 512
#define HH 1024
#define MM (TT * BB)   // 65536 rows for the batched GEMM

typedef _Float16 f16;
typedef _Float16 f16x8 __attribute__((ext_vector_type(8)));
typedef float f32x4 __attribute__((ext_vector_type(4)));

// ---------------------------------------------------------------- converts
__global__ void cvt_f32_to_f16(const float* __restrict__ src,
                               f16* __restrict__ dst, int n) {
    int i = blockIdx.x * blockDim.x + threadIdx.x;
    int idx = i * 8;
    if (idx + 8 <= n) {
        float4 a = *reinterpret_cast<const float4*>(src + idx);
        float4 b = *reinterpret_cast<const float4*>(src + idx + 4);
        f16x8 o;
        o[0] = (f16)a.x; o[1] = (f16)a.y; o[2] = (f16)a.z; o[3] = (f16)a.w;
        o[4] = (f16)b.x; o[5] = (f16)b.y; o[6] = (f16)b.z; o[7] = (f16)b.w;
        *reinterpret_cast<f16x8*>(dst + idx) = o;
    } else {
        for (int k = idx; k < n; ++k) dst[k] = (f16)src[k];
    }
}

// ---------------------------------------------------------------- GEMM
// C[M,N] (f32) = A[M,K] (f16, row-major) * W[N,K]^T (f16, row-major) + bias[N]
// 128x128 tile, BK=32, 4 waves (2x2 of 64x64), 16x16x32 f16 MFMA.
// Staging via global_load_lds width=16 (linear LDS dest).
__device__ __forceinline__ void gload16(const void* g, void* l) {
    __builtin_amdgcn_global_load_lds(
        (const __attribute__((address_space(1))) void*)g,
        (__attribute__((address_space(3))) void*)l, 16, 0, 0);
}

__global__ __launch_bounds__(256) void gemm_f16(
    const f16* __restrict__ A, const f16* __restrict__ W,
    const float* __restrict__ bias, float* __restrict__ C,
    int M, int N, int K) {
    __shared__ f16 Alds[128 * 32];
    __shared__ f16 Blds[128 * 32];

    const int tid  = threadIdx.x;
    const int lane = tid & 63;
    const int wave = tid >> 6;
    const int wr = wave >> 1;        // wave row (0..1) -> 64-row strip
    const int wc = wave & 1;         // wave col (0..1) -> 64-col strip
    const int brow = blockIdx.x * 128;
    const int bcol = blockIdx.y * 128;
    const int lr = lane & 15;        // fragment row/col within 16
    const int kg = (lane >> 4) * 8;  // k-group offset (8 contiguous k)

    f32x4 acc[4][4] = {};

    for (int k0 = 0; k0 < K; k0 += 32) {
        __syncthreads();  // previous compute done before LDS overwrite
        #pragma unroll
        for (int i = 0; i < 2; ++i) {
            int e = (i * 256 + tid) * 8;   // element index in 128x32 tile
            int r = e >> 5;                // row 0..127
            int c = e & 31;                // col 0..31 (multiple of 8)
            gload16(A + (size_t)(brow + r) * K + (k0 + c), &Alds[e]);
            gload16(W + (size_t)(bcol + r) * K + (k0 + c), &Blds[e]);
        }
        __syncthreads();  // compiler drains vmcnt(0) before barrier

        f16x8 af[4], bf[4];
        #pragma unroll
        for (int m = 0; m < 4; ++m)
            af[m] = *reinterpret_cast<const f16x8*>(
                &Alds[(wr * 64 + m * 16 + lr) * 32 + kg]);
        #pragma unroll
        for (int n = 0; n < 4; ++n)
            bf[n] = *reinterpret_cast<const f16x8*>(
                &Blds[(wc * 64 + n * 16 + lr) * 32 + kg]);

        #pragma unroll
        for (int m = 0; m < 4; ++m)
            #pragma unroll
            for (int n = 0; n < 4; ++n)
                acc[m][n] = __builtin_amdgcn_mfma_f32_16x16x32_f16(
                    af[m], bf[n], acc[m][n], 0, 0, 0);
    }

    // epilogue: bias + store. C/D layout: col = lane&15, row = (lane>>4)*4 + j
    #pragma unroll
    for (int n = 0; n < 4; ++n) {
        int col = bcol + wc * 64 + n * 16 + lr;
        float bv = bias[col];
        #pragma unroll
        for (int m = 0; m < 4; ++m) {
            int row0 = brow + wr * 64 + m * 16 + (lane >> 4) * 4;
            #pragma unroll
            for (int j = 0; j < 4; ++j) {
                C[(size_t)(row0 + j) * N + col] = acc[m][n][j] + bv;
            }
        }
    }
}

// ---------------------------------------------------------------- scan
// h_t = tanh(pre_t + h_{t-1} * w), one thread per (b,h) element.
// PF-deep load pipeline hides HBM latency under the serial tanh chain.
// NOTE: for the in-place variant (pre == out) reads of pre[t+PF] never
// touch locations written at <= t, so in-place is safe.
template <typename TO>
__global__ void scan_kernel(const float* pre, const float* __restrict__ w,
                            TO* out) {
    const int S = BB * HH;  // 65536
    int idx = blockIdx.x * blockDim.x + threadIdx.x;
    if (idx >= S) return;
    float wv = w[idx & (HH - 1)];

    constexpr int PF = 32;
    float buf[PF];
    #pragma unroll
    for (int i = 0; i < PF; ++i) buf[i] = pre[(size_t)i * S + idx];

    float h = 0.f;
    for (int t0 = 0; t0 < TT; t0 += PF) {
        #pragma unroll
        for (int i = 0; i < PF; ++i) {
            int tp = t0 + i + PF;
            float nv = (tp < TT) ? pre[(size_t)tp * S + idx] : 0.f;
            h = tanhf(fmaf(h, wv, buf[i]));
            out[(size_t)(t0 + i) * S + idx] = (TO)h;
            buf[i] = nv;
        }
    }
}

__global__ void zero_kernel(float* p, int n) {
    int i = blockIdx.x * blockDim.x + threadIdx.x;
    if (i < n) p[i] = 0.f;
}

// ---------------------------------------------------------------- launch
extern "C" void kernel_launch(void* const* d_in, const int* in_sizes, int n_in,
                              void* d_out, int out_size, void* d_ws, size_t ws_size,
                              hipStream_t stream) {
    const float* x  = (const float*)d_in[0];  // [T,B,D]
    const float* W0 = (const float*)d_in[1];  // [H,D]
    const float* w0 = (const float*)d_in[2];  // [H]
    const float* b0 = (const float*)d_in[3];  // [H]
    const float* W1 = (const float*)d_in[4];  // [H,H]
    const float* w1 = (const float*)d_in[5];  // [H]
    const float* b1 = (const float*)d_in[6];  // [H]
    float* out = (float*)d_out;

    // ws layout:
    //   [0, M*H*2)            : big f16 buffer (x_f16 first, then out0_f16)
    //   [M*H*2, +H*D*2)       : W0 f16
    //   [.., +H*H*2)          : W1 f16
    f16* big = (f16*)d_ws;
    f16* W0h = (f16*)((char*)d_ws + (size_t)MM * HH * sizeof(f16));
    f16* W1h = W0h + (size_t)HH * DD;

    // 1) convert x and weights to f16
    {
        int n = MM * DD;  // 33,554,432
        cvt_f32_to_f16<<<n / 8 / 256, 256, 0, stream>>>(x, big, n);
    }
    cvt_f32_to_f16<<<(HH * DD) / 8 / 256, 256, 0, stream>>>(W0, W0h, HH * DD);
    cvt_f32_to_f16<<<(HH * HH) / 8 / 256, 256, 0, stream>>>(W1, W1h, HH * HH);

    // 2) pre0 = x_f16 @ W0^T + b0  -> d_out (scratch)
    gemm_f16<<<dim3(MM / 128, HH / 128), 256, 0, stream>>>(
        big, W0h, b0, out, MM, HH, DD);

    // 3) scan layer 0 -> out0 (f16) into ws (overwrites x_f16; no longer needed)
    scan_kernel<f16><<<(BB * HH) / 256, 256, 0, stream>>>(out, w0, big);

    // 4) pre1 = out0_f16 @ W1^T + b1 -> d_out (overwrite pre0)
    gemm_f16<<<dim3(MM / 128, HH / 128), 256, 0, stream>>>(
        big, W1h, b1, out, MM, HH, HH);

    // 5) scan layer 1 in place on d_out (f32 out)
    scan_kernel<float><<<(BB * HH) / 256, 256, 0, stream>>>(out, w1, out);

    // 6) hidden output: zeros [2,B,H] appended after [T,B,H]
    zero_kernel<<<(2 * BB * HH) / 256, 256, 0, stream>>>(
        out + (size_t)MM * HH, 2 * BB * HH);
}